// Round 1
// baseline (155.443 us; speedup 1.0000x reference)
//
#include <hip/hip_runtime.h>

// MHA: B=4 T=1024 E=1024 H=16 D=64, causal, f32 in/out, bf16 internal compute.
// Pipeline: cast(f32->bf16) -> GEMM1 (QKV, 4096x3072x1024) -> flash attn -> GEMM2 (+bias)

#define T_SZ 1024
#define E_SZ 1024
#define H_SZ 16
#define D_SZ 64

typedef __attribute__((ext_vector_type(8))) short bf16x8;
typedef __attribute__((ext_vector_type(4))) float f32x4;

static __device__ __forceinline__ unsigned short f2b(float f) {
  unsigned int u = __builtin_bit_cast(unsigned int, f);
  u += 0x7fffu + ((u >> 16) & 1u);   // RNE
  return (unsigned short)(u >> 16);
}

static __device__ __forceinline__ void load_lds16(const void* g, void* l) {
  __builtin_amdgcn_global_load_lds(
      (const __attribute__((address_space(1))) void*)g,
      (__attribute__((address_space(3))) void*)l, 16, 0, 0);
}

// ---------------- cast f32 -> bf16, 4 elems/thread ----------------
__global__ void cast_f32_bf16(const float* __restrict__ in,
                              unsigned short* __restrict__ out, int n4) {
  int i = blockIdx.x * blockDim.x + threadIdx.x;
  if (i >= n4) return;
  float4 v = reinterpret_cast<const float4*>(in)[i];
  ushort4 o;
  o.x = f2b(v.x); o.y = f2b(v.y); o.z = f2b(v.z); o.w = f2b(v.w);
  reinterpret_cast<ushort4*>(out)[i] = o;
}

// ---------------- GEMM C[M,N] = A[M,K] * B[N,K]^T ----------------
// 128x128 tile, 4 waves (each 64x64 = 4x4 frags of 16x16), BK=32.
// EPI=0: scatter bf16 into Q/K/V [B,H,T,D].  EPI=1: f32 + bias -> out.
template <int EPI>
__global__ void gemm_bt(const unsigned short* __restrict__ A,
                        const unsigned short* __restrict__ Bm,
                        int M, int N, int K,
                        float* __restrict__ outF, const float* __restrict__ bias,
                        unsigned short* __restrict__ Qb,
                        unsigned short* __restrict__ Kb,
                        unsigned short* __restrict__ Vb) {
  __shared__ __align__(16) char lds[16384];   // As 8KB | Bs 8KB
  const int tid = threadIdx.x;
  const int wid = tid >> 6;
  const int lane = tid & 63;
  const int llo = lane & 15, lhi = lane >> 4;
  const int row0 = blockIdx.x * 128, col0 = blockIdx.y * 128;
  const int wr = (wid >> 1) * 64, wc = (wid & 1) * 64;

  f32x4 acc[4][4];
#pragma unroll
  for (int m = 0; m < 4; ++m)
#pragma unroll
    for (int n = 0; n < 4; ++n) {
      f32x4 z = {0.f, 0.f, 0.f, 0.f};
      acc[m][n] = z;
    }

  for (int kt = 0; kt < K; kt += 32) {
#pragma unroll
    for (int c = 0; c < 2; ++c) {
      int off = c * 4096 + tid * 16;       // byte offset in 8KB tile
      int r = off >> 6, cb = off & 63;     // row, byte-in-row (BK=32 bf16 = 64B)
      load_lds16((const char*)A + ((size_t)(row0 + r) * K + kt) * 2 + cb,
                 lds + c * 4096 + wid * 1024);
      load_lds16((const char*)Bm + ((size_t)(col0 + r) * K + kt) * 2 + cb,
                 lds + 8192 + c * 4096 + wid * 1024);
    }
    __syncthreads();

    bf16x8 af[4], bfr[4];
#pragma unroll
    for (int m = 0; m < 4; ++m)
      af[m] = *reinterpret_cast<const bf16x8*>(lds + (wr + m * 16 + llo) * 64 + lhi * 16);
#pragma unroll
    for (int n = 0; n < 4; ++n)
      bfr[n] = *reinterpret_cast<const bf16x8*>(lds + 8192 + (wc + n * 16 + llo) * 64 + lhi * 16);
#pragma unroll
    for (int m = 0; m < 4; ++m)
#pragma unroll
      for (int n = 0; n < 4; ++n)
        acc[m][n] = __builtin_amdgcn_mfma_f32_16x16x32_bf16(af[m], bfr[n], acc[m][n], 0, 0, 0);
    __syncthreads();
  }

#pragma unroll
  for (int m = 0; m < 4; ++m)
#pragma unroll
    for (int n = 0; n < 4; ++n)
#pragma unroll
      for (int r = 0; r < 4; ++r) {
        int grow = row0 + wr + m * 16 + lhi * 4 + r;
        int gcol = col0 + wc + n * 16 + llo;
        float v = acc[m][n][r];
        if (EPI == 0) {
          // grow = b*1024+t ; gcol = which*1024 + h*64 + d -> [B,H,T,D]
          int b = grow >> 10, t = grow & 1023;
          int which = gcol >> 10, hd = gcol & 1023;
          unsigned short* dst = (which == 0) ? Qb : (which == 1) ? Kb : Vb;
          dst[((size_t)((b * H_SZ + (hd >> 6)) * T_SZ + t)) * D_SZ + (hd & 63)] = f2b(v);
        } else {
          outF[(size_t)grow * N + gcol] = v + bias[gcol];
        }
      }
}

// ---------------- flash attention, causal ----------------
// grid (T/64, B*H), 256 thr. Wave w owns q rows [qbase+w*16, +16).
// K tile [64 keys][64 d] in LDS (XOR-swizzled), V transposed [64 d][64 keys]
// (swizzled), P per-wave [16][64] bf16 (swizzled).
__global__ void attn_kernel(const unsigned short* __restrict__ Q,
                            const unsigned short* __restrict__ K,
                            const unsigned short* __restrict__ V,
                            unsigned short* __restrict__ O) {
  __shared__ __align__(16) char smem[24576];  // Ks 8KB | Vt 8KB | Ps 4*2KB
  const int tid = threadIdx.x, wid = tid >> 6, lane = tid & 63;
  const int llo = lane & 15, lhi = lane >> 4;
  const int qtile = blockIdx.x;
  const int bh = blockIdx.y;
  const int qbase = qtile * 64;
  const size_t bhbase = (size_t)bh * T_SZ * D_SZ;

  char* Ks = smem;
  char* Vt = smem + 8192;
  char* Ps = smem + 16384 + wid * 2048;

  // Q A-frags: lane holds row llo, k = seg*32 + lhi*8 + e
  bf16x8 aq[2];
  {
    const unsigned short* qp = Q + bhbase + (size_t)(qbase + wid * 16 + llo) * D_SZ + lhi * 8;
    aq[0] = *reinterpret_cast<const bf16x8*>(qp);
    aq[1] = *reinterpret_cast<const bf16x8*>(qp + 32);
  }

  f32x4 oacc[4];
  float mrun[4], lrun[4];
#pragma unroll
  for (int dc = 0; dc < 4; ++dc) {
    f32x4 z = {0.f, 0.f, 0.f, 0.f};
    oacc[dc] = z;
  }
#pragma unroll
  for (int r = 0; r < 4; ++r) { mrun[r] = -1e30f; lrun[r] = 0.f; }

  const float scale = 0.125f;  // 1/sqrt(64)

  for (int it = 0; it <= qtile; ++it) {
    const int kv = it * 64;
    // stage K: linear LDS dest, source column pre-swizzled (read uses same XOR)
#pragma unroll
    for (int c = 0; c < 2; ++c) {
      int off = c * 4096 + tid * 16;
      int key = off >> 7, inrow = off & 127;
      int srow = inrow ^ ((key & 7) << 4);
      load_lds16((const char*)(K + bhbase + (size_t)(kv + key) * D_SZ) + srow,
                 Ks + c * 4096 + wid * 1024);
    }
    // stage V transposed: Vt[d][key], swizzled
#pragma unroll
    for (int c = 0; c < 2; ++c) {
      int key = c * 32 + (tid >> 3);
      int d0 = (tid & 7) * 8;
      bf16x8 vv = *reinterpret_cast<const bf16x8*>(V + bhbase + (size_t)(kv + key) * D_SZ + d0);
#pragma unroll
      for (int j = 0; j < 8; ++j)
        *reinterpret_cast<unsigned short*>(Vt + (d0 + j) * 128 + ((key * 2) ^ (j << 4))) =
            (unsigned short)vv[j];
    }
    __syncthreads();

    // S = Q K^T : 4 key-chunk frags
    f32x4 sacc[4];
#pragma unroll
    for (int c = 0; c < 4; ++c) { f32x4 z = {0.f, 0.f, 0.f, 0.f}; sacc[c] = z; }
#pragma unroll
    for (int seg = 0; seg < 2; ++seg)
#pragma unroll
      for (int c = 0; c < 4; ++c) {
        int key = c * 16 + llo;
        bf16x8 bk = *reinterpret_cast<const bf16x8*>(
            Ks + key * 128 + ((seg * 64 + lhi * 16) ^ ((key & 7) << 4)));
        sacc[c] = __builtin_amdgcn_mfma_f32_16x16x32_bf16(aq[seg], bk, sacc[c], 0, 0, 0);
      }

    // scale + causal mask + row max
    float pm[4];
#pragma unroll
    for (int r = 0; r < 4; ++r) pm[r] = -1e30f;
    const bool diag = (it == qtile);
#pragma unroll
    for (int c = 0; c < 4; ++c)
#pragma unroll
      for (int r = 0; r < 4; ++r) {
        float s = sacc[c][r] * scale;
        if (diag) {
          int key_g = kv + c * 16 + llo;
          int q_g = qbase + wid * 16 + lhi * 4 + r;
          if (key_g > q_g) s = -1e30f;
        }
        sacc[c][r] = s;
        pm[r] = fmaxf(pm[r], s);
      }
#pragma unroll
    for (int off = 8; off >= 1; off >>= 1)
#pragma unroll
      for (int r = 0; r < 4; ++r)
        pm[r] = fmaxf(pm[r], __shfl_xor(pm[r], off, 64));

    float alpha[4], psum[4];
#pragma unroll
    for (int r = 0; r < 4; ++r) {
      float mnew = fmaxf(mrun[r], pm[r]);
      alpha[r] = __expf(mrun[r] - mnew);
      mrun[r] = mnew;
      psum[r] = 0.f;
    }
    // P = exp(s-m) -> bf16 to per-wave LDS (swizzled rows of 128B)
#pragma unroll
    for (int c = 0; c < 4; ++c)
#pragma unroll
      for (int r = 0; r < 4; ++r) {
        float p = __expf(sacc[c][r] - mrun[r]);
        psum[r] += p;
        int qr = lhi * 4 + r;
        int key = c * 16 + llo;
        *reinterpret_cast<unsigned short*>(
            Ps + qr * 128 + ((key * 2) ^ ((qr & 7) << 4))) = f2b(p);
      }
#pragma unroll
    for (int off = 8; off >= 1; off >>= 1)
#pragma unroll
      for (int r = 0; r < 4; ++r)
        psum[r] += __shfl_xor(psum[r], off, 64);
#pragma unroll
    for (int r = 0; r < 4; ++r) lrun[r] = lrun[r] * alpha[r] + psum[r];
#pragma unroll
    for (int dc = 0; dc < 4; ++dc)
#pragma unroll
      for (int r = 0; r < 4; ++r) oacc[dc][r] *= alpha[r];

    // O += P V : A = P frag (row llo, k = key), B = Vt
#pragma unroll
    for (int seg = 0; seg < 2; ++seg) {
      bf16x8 ap = *reinterpret_cast<const bf16x8*>(
          Ps + llo * 128 + ((seg * 64 + lhi * 16) ^ ((llo & 7) << 4)));
#pragma unroll
      for (int dc = 0; dc < 4; ++dc) {
        int d = dc * 16 + llo;
        bf16x8 bv = *reinterpret_cast<const bf16x8*>(
            Vt + d * 128 + ((seg * 64 + lhi * 16) ^ ((d & 7) << 4)));
        oacc[dc] = __builtin_amdgcn_mfma_f32_16x16x32_bf16(ap, bv, oacc[dc], 0, 0, 0);
      }
    }
    __syncthreads();
  }

  // normalize + store O[b][t][h*64+d] bf16
  const int b = bh >> 4, h = bh & 15;
#pragma unroll
  for (int dc = 0; dc < 4; ++dc)
#pragma unroll
    for (int r = 0; r < 4; ++r) {
      int t = qbase + wid * 16 + lhi * 4 + r;
      float v = oacc[dc][r] / lrun[r];
      O[((size_t)b * T_SZ + t) * E_SZ + h * D_SZ + dc * 16 + llo] = f2b(v);
    }
}

// ---------------- launch ----------------
extern "C" void kernel_launch(void* const* d_in, const int* in_sizes, int n_in,
                              void* d_out, int out_size, void* d_ws, size_t ws_size,
                              hipStream_t stream) {
  const float* x  = (const float*)d_in[0];
  const float* Wq = (const float*)d_in[1];
  const float* Wk = (const float*)d_in[2];
  const float* Wv = (const float*)d_in[3];
  const float* Wp = (const float*)d_in[4];
  const float* bp = (const float*)d_in[5];
  float* out = (float*)d_out;

  char* ws = (char*)d_ws;
  unsigned short* xb   = (unsigned short*)(ws);                    // 8 MB [4096,1024]
  unsigned short* wqkv = (unsigned short*)(ws + (8u << 20));       // 6 MB [3072,1024]
  unsigned short* wp   = (unsigned short*)(ws + (14u << 20));      // 2 MB [1024,1024]
  unsigned short* Qb   = (unsigned short*)(ws + (16u << 20));      // 8 MB [B,H,T,D]
  unsigned short* Kb   = (unsigned short*)(ws + (24u << 20));      // 8 MB
  unsigned short* Vb   = (unsigned short*)(ws + (32u << 20));      // 8 MB
  unsigned short* Ob   = (unsigned short*)(ws + (40u << 20));      // 8 MB [B,T,E]

  // casts
  cast_f32_bf16<<<4096, 256, 0, stream>>>(x, xb, 1048576);
  cast_f32_bf16<<<1024, 256, 0, stream>>>(Wq, wqkv,            262144);
  cast_f32_bf16<<<1024, 256, 0, stream>>>(Wk, wqkv + 1048576,  262144);
  cast_f32_bf16<<<1024, 256, 0, stream>>>(Wv, wqkv + 2097152,  262144);
  cast_f32_bf16<<<1024, 256, 0, stream>>>(Wp, wp, 262144);

  // QKV projection: [4096,3072] = xb * wqkv^T, scattered to Q/K/V
  gemm_bt<0><<<dim3(32, 24), 256, 0, stream>>>(xb, wqkv, 4096, 3072, 1024,
                                               nullptr, nullptr, Qb, Kb, Vb);
  // attention
  attn_kernel<<<dim3(16, 64), 256, 0, stream>>>(Qb, Kb, Vb, Ob);
  // output projection + bias
  gemm_bt<1><<<dim3(32, 8), 256, 0, stream>>>(Ob, wp, 4096, 1024, 1024,
                                              out, bp, nullptr, nullptr, nullptr);
}

// Round 4
// 108.023 us; speedup vs baseline: 1.4390x; 1.4390x over previous
//
#include <hip/hip_runtime.h>

// MHA: B=4 T=1024 E=1024 H=16 D=64, causal, f32 in/out, bf16 internal compute.
// cast -> GEMM1 (QKV; V written transposed) -> flash attn (S^T layout) -> GEMM2 (+bias)

#define T_SZ 1024
#define E_SZ 1024
#define H_SZ 16
#define D_SZ 64

typedef __attribute__((ext_vector_type(8))) short bf16x8;
typedef __attribute__((ext_vector_type(4))) short bf16x4;
typedef __attribute__((ext_vector_type(4))) float f32x4;

static __device__ __forceinline__ unsigned short f2b(float f) {
  unsigned int u = __builtin_bit_cast(unsigned int, f);
  u += 0x7fffu + ((u >> 16) & 1u);   // RNE
  return (unsigned short)(u >> 16);
}

static __device__ __forceinline__ unsigned int cvt_pk(float lo, float hi) {
  unsigned int r;
  asm("v_cvt_pk_bf16_f32 %0, %1, %2" : "=v"(r) : "v"(lo), "v"(hi));
  return r;
}

static __device__ __forceinline__ void load_lds16(const void* g, void* l) {
  __builtin_amdgcn_global_load_lds(
      (const __attribute__((address_space(1))) void*)g,
      (__attribute__((address_space(3))) void*)l, 16, 0, 0);
}

// ---------------- fused cast f32 -> bf16 ----------------
__global__ void cast_all(const float* __restrict__ x, const float* __restrict__ wq,
                         const float* __restrict__ wk, const float* __restrict__ wv,
                         const float* __restrict__ wp,
                         unsigned short* __restrict__ xb,
                         unsigned short* __restrict__ wqkvb,
                         unsigned short* __restrict__ wpb) {
  int b = blockIdx.x;
  const float4* src;
  ushort4* dst;
  int i;
  if (b < 4096) {
    src = (const float4*)x; dst = (ushort4*)xb; i = b * 256 + threadIdx.x;
  } else {
    int a = (b - 4096) >> 10;
    i = ((b - 4096) & 1023) * 256 + threadIdx.x;
    src = (const float4*)(a == 0 ? wq : a == 1 ? wk : a == 2 ? wv : wp);
    dst = (ushort4*)(a == 3 ? wpb : wqkvb + (size_t)a * 1048576);
  }
  float4 v = src[i];
  ushort4 o;
  o.x = f2b(v.x); o.y = f2b(v.y); o.z = f2b(v.z); o.w = f2b(v.w);
  dst[i] = o;
}

// ---------------- GEMM C[M,N] = A[M,K] * B[N,K]^T ----------------
template <int EPI>
__global__ void gemm_bt(const unsigned short* __restrict__ A,
                        const unsigned short* __restrict__ Bm,
                        int M, int N, int K,
                        float* __restrict__ outF, const float* __restrict__ bias,
                        unsigned short* __restrict__ Qb,
                        unsigned short* __restrict__ Kb,
                        unsigned short* __restrict__ Vtb) {
  __shared__ __align__(16) char lds[16384];
  const int tid = threadIdx.x;
  const int wid = tid >> 6;
  const int lane = tid & 63;
  const int llo = lane & 15, lhi = lane >> 4;
  const int row0 = blockIdx.x * 128, col0 = blockIdx.y * 128;
  const int wr = (wid >> 1) * 64, wc = (wid & 1) * 64;

  f32x4 acc[4][4];
#pragma unroll
  for (int m = 0; m < 4; ++m)
#pragma unroll
    for (int n = 0; n < 4; ++n) {
      f32x4 z = {0.f, 0.f, 0.f, 0.f};
      acc[m][n] = z;
    }

  for (int kt = 0; kt < K; kt += 32) {
#pragma unroll
    for (int c = 0; c < 2; ++c) {
      int off = c * 4096 + tid * 16;
      int r = off >> 6, cb = off & 63;
      load_lds16((const char*)A + ((size_t)(row0 + r) * K + kt) * 2 + cb,
                 lds + c * 4096 + wid * 1024);
      load_lds16((const char*)Bm + ((size_t)(col0 + r) * K + kt) * 2 + cb,
                 lds + 8192 + c * 4096 + wid * 1024);
    }
    __syncthreads();

    bf16x8 af[4], bfr[4];
#pragma unroll
    for (int m = 0; m < 4; ++m)
      af[m] = *reinterpret_cast<const bf16x8*>(lds + (wr + m * 16 + llo) * 64 + lhi * 16);
#pragma unroll
    for (int n = 0; n < 4; ++n)
      bfr[n] = *reinterpret_cast<const bf16x8*>(lds + 8192 + (wc + n * 16 + llo) * 64 + lhi * 16);
#pragma unroll
    for (int m = 0; m < 4; ++m)
#pragma unroll
      for (int n = 0; n < 4; ++n)
        acc[m][n] = __builtin_amdgcn_mfma_f32_16x16x32_bf16(af[m], bfr[n], acc[m][n], 0, 0, 0);
    __syncthreads();
  }

#pragma unroll
  for (int m = 0; m < 4; ++m)
#pragma unroll
    for (int n = 0; n < 4; ++n)
#pragma unroll
      for (int r = 0; r < 4; ++r) {
        int grow = row0 + wr + m * 16 + lhi * 4 + r;
        int gcol = col0 + wc + n * 16 + llo;
        float v = acc[m][n][r];
        if (EPI == 0) {
          int b = grow >> 10, t = grow & 1023;
          int which = gcol >> 10, hd = gcol & 1023;
          int h = hd >> 6, d = hd & 63;
          unsigned short val = f2b(v);
          if (which == 2)
            Vtb[(((size_t)(b * H_SZ + h)) * D_SZ + d) * T_SZ + t] = val;
          else {
            unsigned short* dst = which ? Kb : Qb;
            dst[(((size_t)(b * H_SZ + h)) * T_SZ + t) * D_SZ + d] = val;
          }
        } else {
          outF[(size_t)grow * N + gcol] = v + bias[gcol];
        }
      }
}

// ---------------- flash attention, causal, S^T layout, single-buffered ----------------
// grid 1024 blocks (XCD-swizzled -> (qtile, bh)), 256 thr = 4 waves x 16 q-rows.
// Per lane: one q-row (q = qbase + wid*16 + llo); holds S^T keys c*16+lhi*4+r.
// K tile [64 key][128B] and Vt tile [64 d][128B] in LDS (XOR swizzle), round-1 protocol:
// stage -> barrier -> compute -> barrier.
__global__ void attn_kernel(const unsigned short* __restrict__ Q,
                            const unsigned short* __restrict__ K,
                            const unsigned short* __restrict__ Vt,
                            unsigned short* __restrict__ O) {
  __shared__ __align__(16) char smem[24576];  // K 8K | V 8K | Ps 4x2K
  const int tid = threadIdx.x, wid = tid >> 6, lane = tid & 63;
  const int llo = lane & 15, lhi = lane >> 4;
  const int fid = blockIdx.y * 16 + blockIdx.x;
  const int wi = (fid & 7) * 128 + (fid >> 3);   // 8 bh per XCD -> K/V L2-resident
  const int qtile = wi & 15;
  const int bh = wi >> 4;
  const int qbase = qtile * 64;
  const size_t bhbase = (size_t)bh * (T_SZ * D_SZ);
  char* Ks = smem;
  char* Vs = smem + 8192;
  char* Ps = smem + 16384 + wid * 2048;

  const int qrow = qbase + wid * 16 + llo;
  bf16x8 bq[2];
  {
    const unsigned short* qp = Q + bhbase + (size_t)qrow * D_SZ + lhi * 8;
    bq[0] = *reinterpret_cast<const bf16x8*>(qp);
    bq[1] = *reinterpret_cast<const bf16x8*>(qp + 32);
  }

  f32x4 oacc[4];
#pragma unroll
  for (int dc = 0; dc < 4; ++dc) {
    f32x4 z = {0.f, 0.f, 0.f, 0.f};
    oacc[dc] = z;
  }
  float mrun = -1e30f, lrun = 0.f;
  const float scale = 0.125f;

  for (int it = 0; it <= qtile; ++it) {
    const int kv = it * 64;
    // stage K and V^T tiles (linear LDS dest, pre-swizzled global source)
#pragma unroll
    for (int c = 0; c < 2; ++c) {
      int off = c * 4096 + tid * 16;
      int row = off >> 7, inb = off & 127;
      int sw = inb ^ ((row & 7) << 4);
      load_lds16((const char*)(K + bhbase + (size_t)(kv + row) * D_SZ) + sw,
                 Ks + c * 4096 + wid * 1024);
      load_lds16((const char*)(Vt + bhbase + (size_t)row * T_SZ + kv) + sw,
                 Vs + c * 4096 + wid * 1024);
    }
    __syncthreads();

    // S^T = K Q^T : A = K rows (keys), B = Q^T
    f32x4 sacc[4];
#pragma unroll
    for (int c = 0; c < 4; ++c) { f32x4 z = {0.f, 0.f, 0.f, 0.f}; sacc[c] = z; }
#pragma unroll
    for (int seg = 0; seg < 2; ++seg)
#pragma unroll
      for (int c = 0; c < 4; ++c) {
        int key = c * 16 + llo;
        bf16x8 ak = *reinterpret_cast<const bf16x8*>(
            Ks + key * 128 + ((seg * 64 + lhi * 16) ^ ((key & 7) << 4)));
        sacc[c] = __builtin_amdgcn_mfma_f32_16x16x32_bf16(ak, bq[seg], sacc[c], 0, 0, 0);
      }

    // softmax: lane holds 16 S^T values of its q-row (keys c*16 + lhi*4 + r)
    const bool diag = (it == qtile);
    float p[4][4];
    float pm = -1e30f;
#pragma unroll
    for (int c = 0; c < 4; ++c)
#pragma unroll
      for (int r = 0; r < 4; ++r) {
        float s = sacc[c][r] * scale;
        if (diag && (kv + c * 16 + lhi * 4 + r > qrow)) s = -1e30f;
        p[c][r] = s;
        pm = fmaxf(pm, s);
      }
    pm = fmaxf(pm, __shfl_xor(pm, 16, 64));
    pm = fmaxf(pm, __shfl_xor(pm, 32, 64));
    float mnew = fmaxf(mrun, pm);
    float alpha = __expf(mrun - mnew);
    mrun = mnew;

    float ps = 0.f;
#pragma unroll
    for (int c = 0; c < 4; ++c) {
#pragma unroll
      for (int r = 0; r < 4; ++r) {
        p[c][r] = __expf(p[c][r] - mnew);
        ps += p[c][r];
      }
      // 4 consecutive keys -> one 8B write (swizzled, conflict-free)
      unsigned int w0 = cvt_pk(p[c][0], p[c][1]);
      unsigned int w1 = cvt_pk(p[c][2], p[c][3]);
      unsigned long long packed = ((unsigned long long)w1 << 32) | w0;
      *reinterpret_cast<bf16x4*>(
          Ps + llo * 128 + ((c * 32 + lhi * 8) ^ ((llo & 7) << 4))) =
          __builtin_bit_cast(bf16x4, packed);
    }
    // Hard fence: all ds_writes of Ps retired before any PV ds_read issues
    // (rule-18 pattern: inline lgkmcnt + sched_barrier).
    asm volatile("s_waitcnt lgkmcnt(0)" ::: "memory");
    __builtin_amdgcn_sched_barrier(0);

    ps += __shfl_xor(ps, 16, 64);
    ps += __shfl_xor(ps, 32, 64);
    lrun = lrun * alpha + ps;
#pragma unroll
    for (int dc = 0; dc < 4; ++dc)
#pragma unroll
      for (int r = 0; r < 4; ++r) oacc[dc][r] *= alpha;

    // O^T += V^T P^T : A = V^T rows (d), B = P^T (from per-wave LDS)
#pragma unroll
    for (int seg = 0; seg < 2; ++seg) {
      bf16x8 bp = *reinterpret_cast<const bf16x8*>(
          Ps + llo * 128 + ((seg * 64 + lhi * 16) ^ ((llo & 7) << 4)));
#pragma unroll
      for (int dc = 0; dc < 4; ++dc) {
        int d = dc * 16 + llo;
        bf16x8 av = *reinterpret_cast<const bf16x8*>(
            Vs + d * 128 + ((seg * 64 + lhi * 16) ^ ((d & 7) << 4)));
        oacc[dc] = __builtin_amdgcn_mfma_f32_16x16x32_bf16(av, bp, oacc[dc], 0, 0, 0);
      }
    }
    __syncthreads();
  }

  // O^T -> O[b][t=q][h*64+d], d = dc*16 + lhi*4 + r
  const int b = bh >> 4, h = bh & 15;
  float inv = 1.f / lrun;
#pragma unroll
  for (int dc = 0; dc < 4; ++dc) {
    unsigned int w0 = cvt_pk(oacc[dc][0] * inv, oacc[dc][1] * inv);
    unsigned int w1 = cvt_pk(oacc[dc][2] * inv, oacc[dc][3] * inv);
    unsigned int* op = reinterpret_cast<unsigned int*>(
        O + ((size_t)b * T_SZ + qrow) * E_SZ + h * D_SZ + dc * 16 + lhi * 4);
    op[0] = w0;
    op[1] = w1;
  }
}

// ---------------- launch ----------------
extern "C" void kernel_launch(void* const* d_in, const int* in_sizes, int n_in,
                              void* d_out, int out_size, void* d_ws, size_t ws_size,
                              hipStream_t stream) {
  const float* x  = (const float*)d_in[0];
  const float* Wq = (const float*)d_in[1];
  const float* Wk = (const float*)d_in[2];
  const float* Wv = (const float*)d_in[3];
  const float* Wp = (const float*)d_in[4];
  const float* bp = (const float*)d_in[5];
  float* out = (float*)d_out;

  char* ws = (char*)d_ws;
  unsigned short* xb   = (unsigned short*)(ws);                    // 8 MB [4096,1024]
  unsigned short* wqkv = (unsigned short*)(ws + (8u << 20));       // 6 MB [3072,1024]
  unsigned short* wp   = (unsigned short*)(ws + (14u << 20));      // 2 MB [1024,1024]
  unsigned short* Qb   = (unsigned short*)(ws + (16u << 20));      // 8 MB [B,H,T,D]
  unsigned short* Kb   = (unsigned short*)(ws + (24u << 20));      // 8 MB [B,H,T,D]
  unsigned short* Vtb  = (unsigned short*)(ws + (32u << 20));      // 8 MB [B,H,D,T]
  unsigned short* Ob   = (unsigned short*)(ws + (40u << 20));      // 8 MB [B,T,E]

  cast_all<<<8192, 256, 0, stream>>>(x, Wq, Wk, Wv, Wp, xb, wqkv, wp);

  gemm_bt<0><<<dim3(32, 24), 256, 0, stream>>>(xb, wqkv, 4096, 3072, 1024,
                                               nullptr, nullptr, Qb, Kb, Vtb);
  attn_kernel<<<dim3(16, 64), 256, 0, stream>>>(Qb, Kb, Vtb, Ob);
  gemm_bt<1><<<dim3(32, 8), 256, 0, stream>>>(Ob, wp, 4096, 1024, 1024,
                                              out, bp, nullptr, nullptr, nullptr);
}

// Round 5
// 103.986 us; speedup vs baseline: 1.4948x; 1.0388x over previous
//
#include <hip/hip_runtime.h>

// MHA: B=4 T=1024 E=1024 H=16 D=64, causal, f32 in/out, bf16 internal compute.
// cast -> GEMM1 (QKV; V written transposed) -> flash attn (S^T layout) -> GEMM2 (+bias)
// R5: GEMM K-loop now 2-phase prefetch (stage t+1 before compute t, 1 barrier/step).

#define T_SZ 1024
#define E_SZ 1024
#define H_SZ 16
#define D_SZ 64

typedef __attribute__((ext_vector_type(8))) short bf16x8;
typedef __attribute__((ext_vector_type(4))) short bf16x4;
typedef __attribute__((ext_vector_type(4))) float f32x4;

static __device__ __forceinline__ unsigned short f2b(float f) {
  unsigned int u = __builtin_bit_cast(unsigned int, f);
  u += 0x7fffu + ((u >> 16) & 1u);   // RNE
  return (unsigned short)(u >> 16);
}

static __device__ __forceinline__ unsigned int cvt_pk(float lo, float hi) {
  unsigned int r;
  asm("v_cvt_pk_bf16_f32 %0, %1, %2" : "=v"(r) : "v"(lo), "v"(hi));
  return r;
}

static __device__ __forceinline__ void load_lds16(const void* g, void* l) {
  __builtin_amdgcn_global_load_lds(
      (const __attribute__((address_space(1))) void*)g,
      (__attribute__((address_space(3))) void*)l, 16, 0, 0);
}

// ---------------- fused cast f32 -> bf16 ----------------
__global__ void cast_all(const float* __restrict__ x, const float* __restrict__ wq,
                         const float* __restrict__ wk, const float* __restrict__ wv,
                         const float* __restrict__ wp,
                         unsigned short* __restrict__ xb,
                         unsigned short* __restrict__ wqkvb,
                         unsigned short* __restrict__ wpb) {
  int b = blockIdx.x;
  const float4* src;
  ushort4* dst;
  int i;
  if (b < 4096) {
    src = (const float4*)x; dst = (ushort4*)xb; i = b * 256 + threadIdx.x;
  } else {
    int a = (b - 4096) >> 10;
    i = ((b - 4096) & 1023) * 256 + threadIdx.x;
    src = (const float4*)(a == 0 ? wq : a == 1 ? wk : a == 2 ? wv : wp);
    dst = (ushort4*)(a == 3 ? wpb : wqkvb + (size_t)a * 1048576);
  }
  float4 v = src[i];
  ushort4 o;
  o.x = f2b(v.x); o.y = f2b(v.y); o.z = f2b(v.z); o.w = f2b(v.w);
  dst[i] = o;
}

// ---------------- GEMM C[M,N] = A[M,K] * B[N,K]^T ----------------
// 128x128 tile, 4 waves, BK=32, double-buffered LDS with prefetch.
template <int EPI>
__global__ void gemm_bt(const unsigned short* __restrict__ A,
                        const unsigned short* __restrict__ Bm,
                        int M, int N, int K,
                        float* __restrict__ outF, const float* __restrict__ bias,
                        unsigned short* __restrict__ Qb,
                        unsigned short* __restrict__ Kb,
                        unsigned short* __restrict__ Vtb) {
  __shared__ __align__(16) char lds[32768];   // 2 x (As 8K | Bs 8K)
  const int tid = threadIdx.x;
  const int wid = tid >> 6;
  const int lane = tid & 63;
  const int llo = lane & 15, lhi = lane >> 4;
  const int row0 = blockIdx.x * 128, col0 = blockIdx.y * 128;
  const int wr = (wid >> 1) * 64, wc = (wid & 1) * 64;

  f32x4 acc[4][4];
#pragma unroll
  for (int m = 0; m < 4; ++m)
#pragma unroll
    for (int n = 0; n < 4; ++n) {
      f32x4 z = {0.f, 0.f, 0.f, 0.f};
      acc[m][n] = z;
    }

  auto stage = [&](int kt, char* base) {
#pragma unroll
    for (int c = 0; c < 2; ++c) {
      int off = c * 4096 + tid * 16;
      int r = off >> 6, cb = off & 63;     // row, byte-in-row (BK=32 bf16 = 64B)
      load_lds16((const char*)A + ((size_t)(row0 + r) * K + kt) * 2 + cb,
                 base + c * 4096 + wid * 1024);
      load_lds16((const char*)Bm + ((size_t)(col0 + r) * K + kt) * 2 + cb,
                 base + 8192 + c * 4096 + wid * 1024);
    }
  };

  stage(0, lds);
  __syncthreads();
  int buf = 0;

  for (int kt = 0; kt < K; kt += 32) {
    char* cur = lds + buf * 16384;
    if (kt + 32 < K) stage(kt + 32, lds + (buf ^ 1) * 16384);

    bf16x8 af[4], bfr[4];
#pragma unroll
    for (int m = 0; m < 4; ++m)
      af[m] = *reinterpret_cast<const bf16x8*>(cur + (wr + m * 16 + llo) * 64 + lhi * 16);
#pragma unroll
    for (int n = 0; n < 4; ++n)
      bfr[n] = *reinterpret_cast<const bf16x8*>(cur + 8192 + (wc + n * 16 + llo) * 64 + lhi * 16);
#pragma unroll
    for (int m = 0; m < 4; ++m)
#pragma unroll
      for (int n = 0; n < 4; ++n)
        acc[m][n] = __builtin_amdgcn_mfma_f32_16x16x32_bf16(af[m], bfr[n], acc[m][n], 0, 0, 0);
    __syncthreads();   // drains vmcnt (t+1 staged) + lgkmcnt; next iter reads buf^1
    buf ^= 1;
  }

#pragma unroll
  for (int m = 0; m < 4; ++m)
#pragma unroll
    for (int n = 0; n < 4; ++n)
#pragma unroll
      for (int r = 0; r < 4; ++r) {
        int grow = row0 + wr + m * 16 + lhi * 4 + r;
        int gcol = col0 + wc + n * 16 + llo;
        float v = acc[m][n][r];
        if (EPI == 0) {
          int b = grow >> 10, t = grow & 1023;
          int which = gcol >> 10, hd = gcol & 1023;
          int h = hd >> 6, d = hd & 63;
          unsigned short val = f2b(v);
          if (which == 2)
            Vtb[(((size_t)(b * H_SZ + h)) * D_SZ + d) * T_SZ + t] = val;
          else {
            unsigned short* dst = which ? Kb : Qb;
            dst[(((size_t)(b * H_SZ + h)) * T_SZ + t) * D_SZ + d] = val;
          }
        } else {
          outF[(size_t)grow * N + gcol] = v + bias[gcol];
        }
      }
}

// ---------------- flash attention, causal, S^T layout, single-buffered ----------------
// (protocol frozen: stage -> barrier -> compute -> barrier; dbuf variant raced, R2/R3)
__global__ void attn_kernel(const unsigned short* __restrict__ Q,
                            const unsigned short* __restrict__ K,
                            const unsigned short* __restrict__ Vt,
                            unsigned short* __restrict__ O) {
  __shared__ __align__(16) char smem[24576];  // K 8K | V 8K | Ps 4x2K
  const int tid = threadIdx.x, wid = tid >> 6, lane = tid & 63;
  const int llo = lane & 15, lhi = lane >> 4;
  const int fid = blockIdx.y * 16 + blockIdx.x;
  const int wi = (fid & 7) * 128 + (fid >> 3);   // 8 bh per XCD -> K/V L2-resident
  const int qtile = wi & 15;
  const int bh = wi >> 4;
  const int qbase = qtile * 64;
  const size_t bhbase = (size_t)bh * (T_SZ * D_SZ);
  char* Ks = smem;
  char* Vs = smem + 8192;
  char* Ps = smem + 16384 + wid * 2048;

  const int qrow = qbase + wid * 16 + llo;
  bf16x8 bq[2];
  {
    const unsigned short* qp = Q + bhbase + (size_t)qrow * D_SZ + lhi * 8;
    bq[0] = *reinterpret_cast<const bf16x8*>(qp);
    bq[1] = *reinterpret_cast<const bf16x8*>(qp + 32);
  }

  f32x4 oacc[4];
#pragma unroll
  for (int dc = 0; dc < 4; ++dc) {
    f32x4 z = {0.f, 0.f, 0.f, 0.f};
    oacc[dc] = z;
  }
  float mrun = -1e30f, lrun = 0.f;
  const float scale = 0.125f;

  for (int it = 0; it <= qtile; ++it) {
    const int kv = it * 64;
#pragma unroll
    for (int c = 0; c < 2; ++c) {
      int off = c * 4096 + tid * 16;
      int row = off >> 7, inb = off & 127;
      int sw = inb ^ ((row & 7) << 4);
      load_lds16((const char*)(K + bhbase + (size_t)(kv + row) * D_SZ) + sw,
                 Ks + c * 4096 + wid * 1024);
      load_lds16((const char*)(Vt + bhbase + (size_t)row * T_SZ + kv) + sw,
                 Vs + c * 4096 + wid * 1024);
    }
    __syncthreads();

    // S^T = K Q^T : A = K rows (keys), B = Q^T
    f32x4 sacc[4];
#pragma unroll
    for (int c = 0; c < 4; ++c) { f32x4 z = {0.f, 0.f, 0.f, 0.f}; sacc[c] = z; }
#pragma unroll
    for (int seg = 0; seg < 2; ++seg)
#pragma unroll
      for (int c = 0; c < 4; ++c) {
        int key = c * 16 + llo;
        bf16x8 ak = *reinterpret_cast<const bf16x8*>(
            Ks + key * 128 + ((seg * 64 + lhi * 16) ^ ((key & 7) << 4)));
        sacc[c] = __builtin_amdgcn_mfma_f32_16x16x32_bf16(ak, bq[seg], sacc[c], 0, 0, 0);
      }

    // softmax: lane holds 16 S^T values of its q-row (keys c*16 + lhi*4 + r)
    const bool diag = (it == qtile);
    float p[4][4];
    float pm = -1e30f;
#pragma unroll
    for (int c = 0; c < 4; ++c)
#pragma unroll
      for (int r = 0; r < 4; ++r) {
        float s = sacc[c][r] * scale;
        if (diag && (kv + c * 16 + lhi * 4 + r > qrow)) s = -1e30f;
        p[c][r] = s;
        pm = fmaxf(pm, s);
      }
    pm = fmaxf(pm, __shfl_xor(pm, 16, 64));
    pm = fmaxf(pm, __shfl_xor(pm, 32, 64));
    float mnew = fmaxf(mrun, pm);
    float alpha = __expf(mrun - mnew);
    mrun = mnew;

    float ps = 0.f;
#pragma unroll
    for (int c = 0; c < 4; ++c) {
#pragma unroll
      for (int r = 0; r < 4; ++r) {
        p[c][r] = __expf(p[c][r] - mnew);
        ps += p[c][r];
      }
      unsigned int w0 = cvt_pk(p[c][0], p[c][1]);
      unsigned int w1 = cvt_pk(p[c][2], p[c][3]);
      unsigned long long packed = ((unsigned long long)w1 << 32) | w0;
      *reinterpret_cast<bf16x4*>(
          Ps + llo * 128 + ((c * 32 + lhi * 8) ^ ((llo & 7) << 4))) =
          __builtin_bit_cast(bf16x4, packed);
    }
    // Hard fence: all ds_writes of Ps retired before any PV ds_read issues.
    asm volatile("s_waitcnt lgkmcnt(0)" ::: "memory");
    __builtin_amdgcn_sched_barrier(0);

    ps += __shfl_xor(ps, 16, 64);
    ps += __shfl_xor(ps, 32, 64);
    lrun = lrun * alpha + ps;
#pragma unroll
    for (int dc = 0; dc < 4; ++dc)
#pragma unroll
      for (int r = 0; r < 4; ++r) oacc[dc][r] *= alpha;

    // O^T += V^T P^T : A = V^T rows (d), B = P^T (from per-wave LDS)
#pragma unroll
    for (int seg = 0; seg < 2; ++seg) {
      bf16x8 bp = *reinterpret_cast<const bf16x8*>(
          Ps + llo * 128 + ((seg * 64 + lhi * 16) ^ ((llo & 7) << 4)));
#pragma unroll
      for (int dc = 0; dc < 4; ++dc) {
        int d = dc * 16 + llo;
        bf16x8 av = *reinterpret_cast<const bf16x8*>(
            Vs + d * 128 + ((seg * 64 + lhi * 16) ^ ((d & 7) << 4)));
        oacc[dc] = __builtin_amdgcn_mfma_f32_16x16x32_bf16(av, bp, oacc[dc], 0, 0, 0);
      }
    }
    __syncthreads();
  }

  // O^T -> O[b][t=q][h*64+d], d = dc*16 + lhi*4 + r
  const int b = bh >> 4, h = bh & 15;
  float inv = 1.f / lrun;
#pragma unroll
  for (int dc = 0; dc < 4; ++dc) {
    unsigned int w0 = cvt_pk(oacc[dc][0] * inv, oacc[dc][1] * inv);
    unsigned int w1 = cvt_pk(oacc[dc][2] * inv, oacc[dc][3] * inv);
    unsigned int* op = reinterpret_cast<unsigned int*>(
        O + ((size_t)b * T_SZ + qrow) * E_SZ + h * D_SZ + dc * 16 + lhi * 4);
    op[0] = w0;
    op[1] = w1;
  }
}

// ---------------- launch ----------------
extern "C" void kernel_launch(void* const* d_in, const int* in_sizes, int n_in,
                              void* d_out, int out_size, void* d_ws, size_t ws_size,
                              hipStream_t stream) {
  const float* x  = (const float*)d_in[0];
  const float* Wq = (const float*)d_in[1];
  const float* Wk = (const float*)d_in[2];
  const float* Wv = (const float*)d_in[3];
  const float* Wp = (const float*)d_in[4];
  const float* bp = (const float*)d_in[5];
  float* out = (float*)d_out;

  char* ws = (char*)d_ws;
  unsigned short* xb   = (unsigned short*)(ws);                    // 8 MB [4096,1024]
  unsigned short* wqkv = (unsigned short*)(ws + (8u << 20));       // 6 MB [3072,1024]
  unsigned short* wp   = (unsigned short*)(ws + (14u << 20));      // 2 MB [1024,1024]
  unsigned short* Qb   = (unsigned short*)(ws + (16u << 20));      // 8 MB [B,H,T,D]
  unsigned short* Kb   = (unsigned short*)(ws + (24u << 20));      // 8 MB [B,H,T,D]
  unsigned short* Vtb  = (unsigned short*)(ws + (32u << 20));      // 8 MB [B,H,D,T]
  unsigned short* Ob   = (unsigned short*)(ws + (40u << 20));      // 8 MB [B,T,E]

  cast_all<<<8192, 256, 0, stream>>>(x, Wq, Wk, Wv, Wp, xb, wqkv, wp);

  gemm_bt<0><<<dim3(32, 24), 256, 0, stream>>>(xb, wqkv, 4096, 3072, 1024,
                                               nullptr, nullptr, Qb, Kb, Vtb);
  attn_kernel<<<dim3(16, 64), 256, 0, stream>>>(Qb, Kb, Vtb, Ob);
  gemm_bt<1><<<dim3(32, 8), 256, 0, stream>>>(Ob, wp, 4096, 1024, 1024,
                                              out, bp, nullptr, nullptr, nullptr);
}